// Round 1
// baseline (563.320 us; speedup 1.0000x reference)
//
#include <hip/hip_runtime.h>
#include <math.h>

// Problem constants
#define BATCH 4
#define HH 56
#define WW 56
#define DMODEL 256
#define NHEADS 8
#define HD 32
#define NNB 49          // 7x7 neighborhood
#define NTOK (BATCH*HH*WW)   // 12544

// ---------------------------------------------------------------------------
// Tiled fp32 GEMM: C[M,N] = A[M,K] @ B[K,N] + bias[N], optional ReLU.
// 64x64 tile, 256 threads, 4x4 micro-tile per thread, BK=16.
// ---------------------------------------------------------------------------
__global__ __launch_bounds__(256)
void gemm_bias_kernel(const float* __restrict__ A, const float* __restrict__ B,
                      const float* __restrict__ bias, float* __restrict__ C,
                      int M, int N, int K, int relu)
{
    __shared__ float As[16][68];   // [k][m], padded (+4) -> conflict-free, 16B-aligned rows
    __shared__ float Bs[16][64];   // [k][n]

    const int tid = threadIdx.x;
    const int bm = blockIdx.y * 64;
    const int bn = blockIdx.x * 64;
    const int tx = tid & 15;        // n group
    const int ty = tid >> 4;        // m group

    // staging indices
    const int la_m = tid >> 2;            // 0..63
    const int la_k = (tid & 3) << 2;      // 0,4,8,12
    const int lb_k = tid >> 4;            // 0..15
    const int lb_n = (tid & 15) << 2;     // 0..60

    float acc[4][4] = {};

    for (int k0 = 0; k0 < K; k0 += 16) {
        // stage A (transpose into As[k][m])
        float4 av = *(const float4*)(A + (size_t)(bm + la_m) * K + k0 + la_k);
        As[la_k + 0][la_m] = av.x;
        As[la_k + 1][la_m] = av.y;
        As[la_k + 2][la_m] = av.z;
        As[la_k + 3][la_m] = av.w;
        // stage B
        float4 bv = *(const float4*)(B + (size_t)(k0 + lb_k) * N + bn + lb_n);
        *(float4*)&Bs[lb_k][lb_n] = bv;
        __syncthreads();

        #pragma unroll
        for (int kk = 0; kk < 16; ++kk) {
            float4 a = *(const float4*)&As[kk][ty << 2];
            float4 b = *(const float4*)&Bs[kk][tx << 2];
            float ar[4] = {a.x, a.y, a.z, a.w};
            float br[4] = {b.x, b.y, b.z, b.w};
            #pragma unroll
            for (int i = 0; i < 4; ++i)
                #pragma unroll
                for (int j = 0; j < 4; ++j)
                    acc[i][j] = fmaf(ar[i], br[j], acc[i][j]);
        }
        __syncthreads();
    }

    // epilogue
    const int n = bn + (tx << 2);
    float4 bia = *(const float4*)(bias + n);
    #pragma unroll
    for (int i = 0; i < 4; ++i) {
        const int m = bm + (ty << 2) + i;
        float4 o;
        o.x = acc[i][0] + bia.x;
        o.y = acc[i][1] + bia.y;
        o.z = acc[i][2] + bia.z;
        o.w = acc[i][3] + bia.w;
        if (relu) {
            o.x = fmaxf(o.x, 0.f); o.y = fmaxf(o.y, 0.f);
            o.z = fmaxf(o.z, 0.f); o.w = fmaxf(o.w, 0.f);
        }
        *(float4*)(C + (size_t)m * N + n) = o;
    }
}

// ---------------------------------------------------------------------------
// Neighborhood attention: one block per token (b,h,w); 256 threads.
// qkv row layout: [q(256) | k(256) | v(256)]; head-major within each.
// ---------------------------------------------------------------------------
__global__ __launch_bounds__(256)
void natt_kernel(const float* __restrict__ qkv, float* __restrict__ att)
{
    const int token = blockIdx.x;
    const int w = token % WW;
    const int h = (token / WW) % HH;
    const int b = token / (WW * HH);
    const int tid = threadIdx.x;

    __shared__ float q_s[DMODEL];
    __shared__ int   nb_s[NNB];
    __shared__ float p_s[NHEADS * NNB];

    // stage q, neighbor token indices
    q_s[tid] = qkv[(size_t)token * 768 + tid];
    if (tid < NNB) {
        int ih0 = h - 3; ih0 = ih0 < 0 ? 0 : (ih0 > HH - 7 ? HH - 7 : ih0);
        int iw0 = w - 3; iw0 = iw0 < 0 ? 0 : (iw0 > WW - 7 ? WW - 7 : iw0);
        const int nh = ih0 + tid / 7;
        const int nw = iw0 + tid % 7;
        nb_s[tid] = (b * HH + nh) * WW + nw;
    }
    __syncthreads();

    // scores: 8 heads x 49 neighbors = 392 dots of length 32
    for (int t = tid; t < NHEADS * NNB; t += 256) {
        const int head = t / NNB;
        const int j = t % NNB;
        const float4* kp = (const float4*)(qkv + (size_t)nb_s[j] * 768 + 256 + head * HD);
        const float4* qp = (const float4*)(q_s + head * HD);
        float s = 0.f;
        #pragma unroll
        for (int d = 0; d < 8; ++d) {
            float4 kv = kp[d], qv = qp[d];
            s += qv.x * kv.x + qv.y * kv.y + qv.z * kv.z + qv.w * kv.w;
        }
        p_s[t] = s * 0.17677669529663687f;  // 1/sqrt(32)
    }
    __syncthreads();

    // softmax per head (8 threads, serial over 49 — cheap)
    if (tid < NHEADS) {
        float* p = p_s + tid * NNB;
        float mx = p[0];
        for (int j = 1; j < NNB; ++j) mx = fmaxf(mx, p[j]);
        float sum = 0.f;
        for (int j = 0; j < NNB; ++j) { float e = __expf(p[j] - mx); p[j] = e; sum += e; }
        const float inv = 1.0f / sum;
        for (int j = 0; j < NNB; ++j) p[j] *= inv;
    }
    __syncthreads();

    // out = sum_j p[j] * v_nb[j]; thread = (head, dim)
    const int head = tid >> 5, d = tid & 31;
    const float* pp = p_s + head * NNB;
    float acc = 0.f;
    for (int j = 0; j < NNB; ++j) {
        acc = fmaf(pp[j], qkv[(size_t)nb_s[j] * 768 + 512 + head * HD + d], acc);
    }
    att[(size_t)token * DMODEL + tid] = acc;
}

// ---------------------------------------------------------------------------
// out = LayerNorm(resid + y) * g + beta; one block per token, 256 threads.
// ---------------------------------------------------------------------------
__global__ __launch_bounds__(256)
void add_ln_kernel(const float* __restrict__ resid, const float* __restrict__ y,
                   const float* __restrict__ g, const float* __restrict__ beta,
                   float* __restrict__ out)
{
    const int row = blockIdx.x;
    const int tid = threadIdx.x;
    const size_t base = (size_t)row * DMODEL;

    __shared__ float red[4];
    __shared__ float stats[2];

    const float t = resid[base + tid] + y[base + tid];

    // mean
    float s = t;
    #pragma unroll
    for (int o = 32; o > 0; o >>= 1) s += __shfl_down(s, o, 64);
    const int wave = tid >> 6, lane = tid & 63;
    if (lane == 0) red[wave] = s;
    __syncthreads();
    if (tid == 0) stats[0] = (red[0] + red[1] + red[2] + red[3]) * (1.0f / 256.0f);
    __syncthreads();
    const float m = stats[0];

    // variance
    const float dv = t - m;
    float s2 = dv * dv;
    #pragma unroll
    for (int o = 32; o > 0; o >>= 1) s2 += __shfl_down(s2, o, 64);
    if (lane == 0) red[wave] = s2;
    __syncthreads();
    if (tid == 0)
        stats[1] = rsqrtf((red[0] + red[1] + red[2] + red[3]) * (1.0f / 256.0f) + 1e-5f);
    __syncthreads();
    const float r = stats[1];

    out[base + tid] = dv * r * g[tid] + beta[tid];
}

// ---------------------------------------------------------------------------
extern "C" void kernel_launch(void* const* d_in, const int* in_sizes, int n_in,
                              void* d_out, int out_size, void* d_ws, size_t ws_size,
                              hipStream_t stream)
{
    const float* x      = (const float*)d_in[0];
    const float* W_qkv  = (const float*)d_in[1];
    const float* b_qkv  = (const float*)d_in[2];
    const float* W_proj = (const float*)d_in[3];
    const float* b_proj = (const float*)d_in[4];
    const float* W1     = (const float*)d_in[5];
    const float* b1     = (const float*)d_in[6];
    const float* W2     = (const float*)d_in[7];
    const float* b2     = (const float*)d_in[8];
    const float* g1     = (const float*)d_in[9];
    const float* be1    = (const float*)d_in[10];
    const float* g2     = (const float*)d_in[11];
    const float* be2    = (const float*)d_in[12];
    float* out = (float*)d_out;

    char* ws = (char*)d_ws;
    const int M = NTOK;  // 12544

    // Region A: max(qkv 12544x768, h 12544x1024) = 12544*1024 floats
    const size_t offA = (size_t)M * 1024 * sizeof(float);
    float* qkv = (float*)ws;                                        // 12544x768
    float* h   = (float*)ws;                                        // 12544x1024 (qkv dead by then)
    float* att = (float*)(ws + offA);                               // 12544x256
    float* f   = att;                                               // reuse (att dead after proj GEMM)
    float* y   = (float*)(ws + offA + (size_t)M * DMODEL * 4);      // 12544x256
    float* xn  = (float*)(ws + offA + 2 * (size_t)M * DMODEL * 4);  // 12544x256

    dim3 blk(256);

    // 1) qkv = x @ W_qkv + b_qkv        (M x 768, K=256)
    gemm_bias_kernel<<<dim3(768 / 64, M / 64), blk, 0, stream>>>(x, W_qkv, b_qkv, qkv, M, 768, 256, 0);

    // 2) neighborhood attention -> att  (M x 256)
    natt_kernel<<<dim3(M), blk, 0, stream>>>(qkv, att);

    // 3) y = att @ W_proj + b_proj      (M x 256, K=256)
    gemm_bias_kernel<<<dim3(256 / 64, M / 64), blk, 0, stream>>>(att, W_proj, b_proj, y, M, 256, 256, 0);

    // 4) xn = LN(x + y)
    add_ln_kernel<<<dim3(M), blk, 0, stream>>>(x, y, g1, be1, xn);

    // 5) h = relu(xn @ W1 + b1)         (M x 1024, K=256)
    gemm_bias_kernel<<<dim3(1024 / 64, M / 64), blk, 0, stream>>>(xn, W1, b1, h, M, 1024, 256, 1);

    // 6) f = h @ W2 + b2                (M x 256, K=1024)
    gemm_bias_kernel<<<dim3(256 / 64, M / 64), blk, 0, stream>>>(h, W2, b2, f, M, 256, 1024, 0);

    // 7) out = LN(xn + f)
    add_ln_kernel<<<dim3(M), blk, 0, stream>>>(xn, f, g2, be2, out);
}

// Round 2
// 355.709 us; speedup vs baseline: 1.5837x; 1.5837x over previous
//
#include <hip/hip_runtime.h>
#include <math.h>

// Problem constants
#define BATCH 4
#define HH 56
#define WW 56
#define DMODEL 256
#define NHEADS 8
#define HD 32
#define NNB 49               // 7x7 neighborhood
#define NTOK (BATCH*HH*WW)   // 12544

typedef __attribute__((ext_vector_type(8))) short s16x8;
typedef __attribute__((ext_vector_type(4))) float f32x4;

__device__ inline unsigned short f2b(float f) {
    union { float f; unsigned int u; } v; v.f = f;
    unsigned int r = v.u + 0x7FFF + ((v.u >> 16) & 1);  // RNE
    return (unsigned short)(r >> 16);
}

// ---------------------------------------------------------------------------
// prep: cast x -> bf16 (row-major) and cast+transpose weights to [N][K] bf16.
// blocks [0,3136): x cast (4 elems/thread). blocks [3136,6208): weights.
// ---------------------------------------------------------------------------
__global__ __launch_bounds__(256)
void prep_kernel(const float* __restrict__ x,
                 const float* __restrict__ Wq, const float* __restrict__ Wp,
                 const float* __restrict__ W1, const float* __restrict__ W2,
                 unsigned short* __restrict__ xb,
                 unsigned short* __restrict__ Wqb, unsigned short* __restrict__ Wpb,
                 unsigned short* __restrict__ W1b, unsigned short* __restrict__ W2b)
{
    const int bid = blockIdx.x, tid = threadIdx.x;
    if (bid < 3136) {
        const size_t i4 = ((size_t)bid * 256 + tid) * 4;
        float4 v = *(const float4*)(x + i4);
        ushort4 o;
        o.x = f2b(v.x); o.y = f2b(v.y); o.z = f2b(v.z); o.w = f2b(v.w);
        *(ushort4*)(xb + i4) = o;
    } else {
        int i = (bid - 3136) * 256 + tid;
        // Wt[n*K+k] = W[k*N+n]; i indexes the output linearly (n = i/K, k = i%K)
        if (i < 196608) {            // W_qkv: K=256, N=768
            int n = i >> 8, k = i & 255;
            Wqb[i] = f2b(Wq[k * 768 + n]);
        } else if ((i -= 196608) < 65536) {   // W_proj: K=256, N=256
            int n = i >> 8, k = i & 255;
            Wpb[i] = f2b(Wp[k * 256 + n]);
        } else if ((i -= 65536) < 262144) {   // W1: K=256, N=1024
            int n = i >> 8, k = i & 255;
            W1b[i] = f2b(W1[k * 1024 + n]);
        } else {                              // W2: K=1024, N=256
            i -= 262144;
            int n = i >> 10, k = i & 1023;
            W2b[i] = f2b(W2[k * 256 + n]);
        }
    }
}

// ---------------------------------------------------------------------------
// bf16 MFMA GEMM: C[M,N] = A[M,K] @ B[K,N] + bias, A bf16 [M][K], Bt bf16 [N][K].
// 128x128 tile, BK=64, 256 threads = 4 waves (2x2), each wave 64x64 via 4x4
// mfma_f32_16x16x32_bf16 tiles. LDS rows padded to 72 bf16 (144B) for bank
// spread + 16B alignment. Epilogue: bias, optional ReLU, fp32 and/or bf16 out.
// ---------------------------------------------------------------------------
__global__ __launch_bounds__(256)
void gemm_mfma(const unsigned short* __restrict__ A, const unsigned short* __restrict__ Bt,
               const float* __restrict__ bias, float* __restrict__ outf,
               unsigned short* __restrict__ outb, int M, int N, int K, int relu)
{
    __shared__ unsigned short As[128 * 72];
    __shared__ unsigned short Bs[128 * 72];

    const int tid = threadIdx.x;
    const int bm = blockIdx.y * 128, bn = blockIdx.x * 128;
    const int wid = tid >> 6, lane = tid & 63;
    const int wm = (wid >> 1) * 64, wn = (wid & 1) * 64;
    const int row16 = lane & 15, quad = lane >> 4;

    // staging: thread t handles row t>>1, half (t&1) of 64 k's (32 bf16 = 4x16B)
    const int srow = tid >> 1, shalf = tid & 1;
    const unsigned short* ag = A  + (size_t)(bm + srow) * K + shalf * 32;
    const unsigned short* bg = Bt + (size_t)(bn + srow) * K + shalf * 32;
    unsigned short* asw = As + srow * 72 + shalf * 32;
    unsigned short* bsw = Bs + srow * 72 + shalf * 32;

    f32x4 acc[4][4] = {};

    for (int k0 = 0; k0 < K; k0 += 64) {
        s16x8 a0 = *(const s16x8*)(ag + k0);
        s16x8 a1 = *(const s16x8*)(ag + k0 + 8);
        s16x8 a2 = *(const s16x8*)(ag + k0 + 16);
        s16x8 a3 = *(const s16x8*)(ag + k0 + 24);
        s16x8 b0 = *(const s16x8*)(bg + k0);
        s16x8 b1 = *(const s16x8*)(bg + k0 + 8);
        s16x8 b2 = *(const s16x8*)(bg + k0 + 16);
        s16x8 b3 = *(const s16x8*)(bg + k0 + 24);
        __syncthreads();   // protect LDS still being read (prev iter)
        *(s16x8*)(asw)      = a0; *(s16x8*)(asw +  8) = a1;
        *(s16x8*)(asw + 16) = a2; *(s16x8*)(asw + 24) = a3;
        *(s16x8*)(bsw)      = b0; *(s16x8*)(bsw +  8) = b1;
        *(s16x8*)(bsw + 16) = b2; *(s16x8*)(bsw + 24) = b3;
        __syncthreads();

        #pragma unroll
        for (int kc = 0; kc < 2; ++kc) {
            s16x8 af[4], bf[4];
            #pragma unroll
            for (int i = 0; i < 4; ++i)
                af[i] = *(const s16x8*)(As + (wm + i * 16 + row16) * 72 + kc * 32 + quad * 8);
            #pragma unroll
            for (int j = 0; j < 4; ++j)
                bf[j] = *(const s16x8*)(Bs + (wn + j * 16 + row16) * 72 + kc * 32 + quad * 8);
            #pragma unroll
            for (int i = 0; i < 4; ++i)
                #pragma unroll
                for (int j = 0; j < 4; ++j)
                    acc[i][j] = __builtin_amdgcn_mfma_f32_16x16x32_bf16(af[i], bf[j], acc[i][j], 0, 0, 0);
        }
    }

    // epilogue: D layout col = lane&15, row = quad*4 + reg  [m89-verified]
    #pragma unroll
    for (int j = 0; j < 4; ++j) {
        const int col = bn + wn + j * 16 + row16;
        const float bb = bias[col];
        #pragma unroll
        for (int i = 0; i < 4; ++i) {
            const int r0 = bm + wm + i * 16 + quad * 4;
            #pragma unroll
            for (int reg = 0; reg < 4; ++reg) {
                float v = acc[i][j][reg] + bb;
                if (relu) v = fmaxf(v, 0.f);
                if (outf) outf[(size_t)(r0 + reg) * N + col] = v;
                if (outb) outb[(size_t)(r0 + reg) * N + col] = f2b(v);
            }
        }
    }
}

// ---------------------------------------------------------------------------
// Neighborhood attention (fp32 in, bf16 out): one block per token; 256 threads.
// qkv row layout: [q(256) | k(256) | v(256)]; head-major within each.
// ---------------------------------------------------------------------------
__global__ __launch_bounds__(256)
void natt_kernel(const float* __restrict__ qkv, unsigned short* __restrict__ att)
{
    const int token = blockIdx.x;
    const int w = token % WW;
    const int h = (token / WW) % HH;
    const int b = token / (WW * HH);
    const int tid = threadIdx.x;

    __shared__ float q_s[DMODEL];
    __shared__ int   nb_s[NNB];
    __shared__ float p_s[NHEADS * NNB];

    q_s[tid] = qkv[(size_t)token * 768 + tid];
    if (tid < NNB) {
        int ih0 = h - 3; ih0 = ih0 < 0 ? 0 : (ih0 > HH - 7 ? HH - 7 : ih0);
        int iw0 = w - 3; iw0 = iw0 < 0 ? 0 : (iw0 > WW - 7 ? WW - 7 : iw0);
        const int nh = ih0 + tid / 7;
        const int nw = iw0 + tid % 7;
        nb_s[tid] = (b * HH + nh) * WW + nw;
    }
    __syncthreads();

    for (int t = tid; t < NHEADS * NNB; t += 256) {
        const int head = t / NNB;
        const int j = t % NNB;
        const float4* kp = (const float4*)(qkv + (size_t)nb_s[j] * 768 + 256 + head * HD);
        const float4* qp = (const float4*)(q_s + head * HD);
        float s = 0.f;
        #pragma unroll
        for (int d = 0; d < 8; ++d) {
            float4 kv = kp[d], qv = qp[d];
            s += qv.x * kv.x + qv.y * kv.y + qv.z * kv.z + qv.w * kv.w;
        }
        p_s[t] = s * 0.17677669529663687f;  // 1/sqrt(32)
    }
    __syncthreads();

    if (tid < NHEADS) {
        float* p = p_s + tid * NNB;
        float mx = p[0];
        for (int j = 1; j < NNB; ++j) mx = fmaxf(mx, p[j]);
        float sum = 0.f;
        for (int j = 0; j < NNB; ++j) { float e = __expf(p[j] - mx); p[j] = e; sum += e; }
        const float inv = 1.0f / sum;
        for (int j = 0; j < NNB; ++j) p[j] *= inv;
    }
    __syncthreads();

    const int head = tid >> 5, d = tid & 31;
    const float* pp = p_s + head * NNB;
    float acc = 0.f;
    for (int j = 0; j < NNB; ++j) {
        acc = fmaf(pp[j], qkv[(size_t)nb_s[j] * 768 + 512 + head * HD + d], acc);
    }
    att[(size_t)token * DMODEL + tid] = f2b(acc);
}

// ---------------------------------------------------------------------------
// out = LayerNorm(resid + y) * g + beta; fp32 out + optional bf16 out.
// ---------------------------------------------------------------------------
__global__ __launch_bounds__(256)
void add_ln_kernel(const float* __restrict__ resid, const float* __restrict__ y,
                   const float* __restrict__ g, const float* __restrict__ beta,
                   float* __restrict__ outf, unsigned short* __restrict__ outb)
{
    const int row = blockIdx.x;
    const int tid = threadIdx.x;
    const size_t base = (size_t)row * DMODEL;

    __shared__ float red[4];
    __shared__ float stats[2];

    const float t = resid[base + tid] + y[base + tid];

    float s = t;
    #pragma unroll
    for (int o = 32; o > 0; o >>= 1) s += __shfl_down(s, o, 64);
    const int wave = tid >> 6, lane = tid & 63;
    if (lane == 0) red[wave] = s;
    __syncthreads();
    if (tid == 0) stats[0] = (red[0] + red[1] + red[2] + red[3]) * (1.0f / 256.0f);
    __syncthreads();
    const float m = stats[0];

    const float dv = t - m;
    float s2 = dv * dv;
    #pragma unroll
    for (int o = 32; o > 0; o >>= 1) s2 += __shfl_down(s2, o, 64);
    if (lane == 0) red[wave] = s2;
    __syncthreads();
    if (tid == 0)
        stats[1] = rsqrtf((red[0] + red[1] + red[2] + red[3]) * (1.0f / 256.0f) + 1e-5f);
    __syncthreads();
    const float r = stats[1];

    const float o = dv * r * g[tid] + beta[tid];
    outf[base + tid] = o;
    if (outb) outb[base + tid] = f2b(o);
}

// ---------------------------------------------------------------------------
extern "C" void kernel_launch(void* const* d_in, const int* in_sizes, int n_in,
                              void* d_out, int out_size, void* d_ws, size_t ws_size,
                              hipStream_t stream)
{
    const float* x      = (const float*)d_in[0];
    const float* W_qkv  = (const float*)d_in[1];
    const float* b_qkv  = (const float*)d_in[2];
    const float* W_proj = (const float*)d_in[3];
    const float* b_proj = (const float*)d_in[4];
    const float* W1     = (const float*)d_in[5];
    const float* b1     = (const float*)d_in[6];
    const float* W2     = (const float*)d_in[7];
    const float* b2     = (const float*)d_in[8];
    const float* g1     = (const float*)d_in[9];
    const float* be1    = (const float*)d_in[10];
    const float* g2     = (const float*)d_in[11];
    const float* be2    = (const float*)d_in[12];
    float* out = (float*)d_out;

    char* ws = (char*)d_ws;
    const int M = NTOK;  // 12544

    // Workspace layout (78.6 MB total, fits the >=90MB ws proven in R1):
    // R1: qkv f32 [M][768] then h bf16 [M][1024]     (38.5 MB)
    // R2: xb bf16 then att bf16 [M][256]             ( 6.4 MB)
    // R3: y f32 then f f32 [M][256]                  (12.8 MB)
    // R4: xn f32 [M][256]                            (12.8 MB)
    // R5: xnb bf16 [M][256]                          ( 6.4 MB)
    // R6: bf16 transposed weights                    ( 1.6 MB)
    float*          qkv  = (float*)ws;
    unsigned short* h    = (unsigned short*)ws;
    unsigned short* xb   = (unsigned short*)(ws + 38535168);
    unsigned short* attb = xb;
    float*          y    = (float*)(ws + 44957696);
    float*          f    = y;
    float*          xn   = (float*)(ws + 57802752);
    unsigned short* xnb  = (unsigned short*)(ws + 70647808);
    unsigned short* Wqb  = (unsigned short*)(ws + 77070336);
    unsigned short* Wpb  = Wqb + 196608;
    unsigned short* W1b  = Wpb + 65536;
    unsigned short* W2b  = W1b + 262144;

    dim3 blk(256);

    // 0) cast x + cast/transpose weights to bf16
    prep_kernel<<<dim3(6208), blk, 0, stream>>>(x, W_qkv, W_proj, W1, W2, xb, Wqb, Wpb, W1b, W2b);

    // 1) qkv = x @ W_qkv + b_qkv   (f32 out for attention)
    gemm_mfma<<<dim3(6, 98), blk, 0, stream>>>(xb, Wqb, b_qkv, qkv, nullptr, M, 768, 256, 0);

    // 2) neighborhood attention -> att (bf16)
    natt_kernel<<<dim3(M), blk, 0, stream>>>(qkv, attb);

    // 3) y = att @ W_proj + b_proj (f32)
    gemm_mfma<<<dim3(2, 98), blk, 0, stream>>>(attb, Wpb, b_proj, y, nullptr, M, 256, 256, 0);

    // 4) xn = LN(x + y)  (f32 + bf16)
    add_ln_kernel<<<dim3(M), blk, 0, stream>>>(x, y, g1, be1, xn, xnb);

    // 5) h = relu(xn @ W1 + b1)  (bf16 only)
    gemm_mfma<<<dim3(8, 98), blk, 0, stream>>>(xnb, W1b, b1, nullptr, h, M, 1024, 256, 1);

    // 6) f = h @ W2 + b2  (f32)
    gemm_mfma<<<dim3(2, 98), blk, 0, stream>>>(h, W2b, b2, f, nullptr, M, 256, 1024, 0);

    // 7) out = LN(xn + f)
    add_ln_kernel<<<dim3(M), blk, 0, stream>>>(xn, f, g2, be2, out, nullptr);
}

// Round 3
// 246.629 us; speedup vs baseline: 2.2841x; 1.4423x over previous
//
#include <hip/hip_runtime.h>
#include <math.h>

// Problem constants
#define BATCH 4
#define HH 56
#define WW 56
#define DMODEL 256
#define NHEADS 8
#define HD 32
#define NNB 49               // 7x7 neighborhood
#define NTOK (BATCH*HH*WW)   // 12544

#define KV_PAD 40            // 32 dims + 8 pad (bf16 elems) -> 20-bank row stride
#define S_PAD 51             // 49 scores + pad (f32) -> 19-bank lane stride

typedef __attribute__((ext_vector_type(8))) short s16x8;
typedef __attribute__((ext_vector_type(4))) float f32x4;

__device__ inline unsigned short f2b(float f) {
    union { float f; unsigned int u; } v; v.f = f;
    unsigned int r = v.u + 0x7FFF + ((v.u >> 16) & 1);  // RNE
    return (unsigned short)(r >> 16);
}
__device__ inline float b2f(unsigned short u) {
    union { float f; unsigned int u; } v; v.u = ((unsigned int)u) << 16;
    return v.f;
}

// ---------------------------------------------------------------------------
// prep: cast x -> bf16 (row-major) and cast+transpose weights to [N][K] bf16.
// ---------------------------------------------------------------------------
__global__ __launch_bounds__(256)
void prep_kernel(const float* __restrict__ x,
                 const float* __restrict__ Wq, const float* __restrict__ Wp,
                 const float* __restrict__ W1, const float* __restrict__ W2,
                 unsigned short* __restrict__ xb,
                 unsigned short* __restrict__ Wqb, unsigned short* __restrict__ Wpb,
                 unsigned short* __restrict__ W1b, unsigned short* __restrict__ W2b)
{
    const int bid = blockIdx.x, tid = threadIdx.x;
    if (bid < 3136) {
        const size_t i4 = ((size_t)bid * 256 + tid) * 4;
        float4 v = *(const float4*)(x + i4);
        ushort4 o;
        o.x = f2b(v.x); o.y = f2b(v.y); o.z = f2b(v.z); o.w = f2b(v.w);
        *(ushort4*)(xb + i4) = o;
    } else {
        int i = (bid - 3136) * 256 + tid;
        if (i < 196608) {            // W_qkv: K=256, N=768
            int n = i >> 8, k = i & 255;
            Wqb[i] = f2b(Wq[k * 768 + n]);
        } else if ((i -= 196608) < 65536) {   // W_proj: K=256, N=256
            int n = i >> 8, k = i & 255;
            Wpb[i] = f2b(Wp[k * 256 + n]);
        } else if ((i -= 65536) < 262144) {   // W1: K=256, N=1024
            int n = i >> 8, k = i & 255;
            W1b[i] = f2b(W1[k * 1024 + n]);
        } else {                              // W2: K=1024, N=256
            i -= 262144;
            int n = i >> 10, k = i & 1023;
            W2b[i] = f2b(W2[k * 256 + n]);
        }
    }
}

// ---------------------------------------------------------------------------
// bf16 MFMA GEMM (unchanged structure): C = A @ Bt^T + bias, 128x128 tile.
// ---------------------------------------------------------------------------
__global__ __launch_bounds__(256)
void gemm_mfma(const unsigned short* __restrict__ A, const unsigned short* __restrict__ Bt,
               const float* __restrict__ bias, float* __restrict__ outf,
               unsigned short* __restrict__ outb, int M, int N, int K, int relu)
{
    __shared__ unsigned short As[128 * 72];
    __shared__ unsigned short Bs[128 * 72];

    const int tid = threadIdx.x;
    const int bm = blockIdx.y * 128, bn = blockIdx.x * 128;
    const int wid = tid >> 6, lane = tid & 63;
    const int wm = (wid >> 1) * 64, wn = (wid & 1) * 64;
    const int row16 = lane & 15, quad = lane >> 4;

    const int srow = tid >> 1, shalf = tid & 1;
    const unsigned short* ag = A  + (size_t)(bm + srow) * K + shalf * 32;
    const unsigned short* bg = Bt + (size_t)(bn + srow) * K + shalf * 32;
    unsigned short* asw = As + srow * 72 + shalf * 32;
    unsigned short* bsw = Bs + srow * 72 + shalf * 32;

    f32x4 acc[4][4] = {};

    for (int k0 = 0; k0 < K; k0 += 64) {
        s16x8 a0 = *(const s16x8*)(ag + k0);
        s16x8 a1 = *(const s16x8*)(ag + k0 + 8);
        s16x8 a2 = *(const s16x8*)(ag + k0 + 16);
        s16x8 a3 = *(const s16x8*)(ag + k0 + 24);
        s16x8 b0 = *(const s16x8*)(bg + k0);
        s16x8 b1 = *(const s16x8*)(bg + k0 + 8);
        s16x8 b2 = *(const s16x8*)(bg + k0 + 16);
        s16x8 b3 = *(const s16x8*)(bg + k0 + 24);
        __syncthreads();
        *(s16x8*)(asw)      = a0; *(s16x8*)(asw +  8) = a1;
        *(s16x8*)(asw + 16) = a2; *(s16x8*)(asw + 24) = a3;
        *(s16x8*)(bsw)      = b0; *(s16x8*)(bsw +  8) = b1;
        *(s16x8*)(bsw + 16) = b2; *(s16x8*)(bsw + 24) = b3;
        __syncthreads();

        #pragma unroll
        for (int kc = 0; kc < 2; ++kc) {
            s16x8 af[4], bf[4];
            #pragma unroll
            for (int i = 0; i < 4; ++i)
                af[i] = *(const s16x8*)(As + (wm + i * 16 + row16) * 72 + kc * 32 + quad * 8);
            #pragma unroll
            for (int j = 0; j < 4; ++j)
                bf[j] = *(const s16x8*)(Bs + (wn + j * 16 + row16) * 72 + kc * 32 + quad * 8);
            #pragma unroll
            for (int i = 0; i < 4; ++i)
                #pragma unroll
                for (int j = 0; j < 4; ++j)
                    acc[i][j] = __builtin_amdgcn_mfma_f32_16x16x32_bf16(af[i], bf[j], acc[i][j], 0, 0, 0);
        }
    }

    #pragma unroll
    for (int j = 0; j < 4; ++j) {
        const int col = bn + wn + j * 16 + row16;
        const float bb = bias[col];
        #pragma unroll
        for (int i = 0; i < 4; ++i) {
            const int r0 = bm + wm + i * 16 + quad * 4;
            #pragma unroll
            for (int reg = 0; reg < 4; ++reg) {
                float v = acc[i][j][reg] + bb;
                if (relu) v = fmaxf(v, 0.f);
                if (outf) outf[(size_t)(r0 + reg) * N + col] = v;
                if (outb) outb[(size_t)(r0 + reg) * N + col] = f2b(v);
            }
        }
    }
}

// ---------------------------------------------------------------------------
// Tiled neighborhood attention. Block = (8x8 query tile, head), 64 threads.
// Stages the 14x14 halo of K,V (one head, bf16) into LDS; each lane handles
// one query entirely from LDS. Scores kept per-lane in a private LDS row.
// ---------------------------------------------------------------------------
__global__ __launch_bounds__(64)
void natt_kernel(const unsigned short* __restrict__ qkvb, unsigned short* __restrict__ att)
{
    const int blk  = blockIdx.x;          // 4*49*8 = 1568
    const int head = blk & 7;
    const int t2   = blk >> 3;            // 0..195
    const int tile = t2 % 49;
    const int b    = t2 / 49;
    const int r0 = (tile / 7) * 8, c0 = (tile % 7) * 8;
    const int hs = min(max(r0 - 3, 0), 42);
    const int ws = min(max(c0 - 3, 0), 42);

    __shared__ unsigned short Ks[196 * KV_PAD];
    __shared__ unsigned short Vs[196 * KV_PAD];
    __shared__ float Ss[64 * S_PAD];

    const int lane = threadIdx.x;

    // ---- stage halo K,V: 4 lanes per token row (16B each), 13 iterations
    #pragma unroll
    for (int it = 0; it < 13; ++it) {
        const int t = it * 16 + (lane >> 2);
        if (t < 196) {
            const int hr = t / 14, hc = t - hr * 14;
            const size_t rb = ((size_t)((b * 56 + hs + hr) * 56 + (ws + hc))) * 768;
            const int d8 = (lane & 3) * 8;
            *(s16x8*)(Ks + t * KV_PAD + d8) = *(const s16x8*)(qkvb + rb + 256 + head * 32 + d8);
            *(s16x8*)(Vs + t * KV_PAD + d8) = *(const s16x8*)(qkvb + rb + 512 + head * 32 + d8);
        }
    }

    // ---- per-lane query setup
    const int q = lane;
    const int qh = r0 + (q >> 3), qw = c0 + (q & 7);
    const int tok = (b * 56 + qh) * 56 + qw;
    const int ro = min(max(qh - 3, 0), 49) - hs;   // 0..7
    const int co = min(max(qw - 3, 0), 49) - ws;   // 0..7

    float qf[32];
    {
        const unsigned short* qp = qkvb + (size_t)tok * 768 + head * 32;
        #pragma unroll
        for (int d8 = 0; d8 < 4; ++d8) {
            s16x8 qv = *(const s16x8*)(qp + d8 * 8);
            #pragma unroll
            for (int e = 0; e < 8; ++e) qf[d8 * 8 + e] = b2f((unsigned short)qv[e]);
        }
    }
    __syncthreads();

    float* srow = Ss + q * S_PAD;

    // ---- scores + running max (all K reads are LDS)
    float mx = -1e30f;
    for (int i = 0; i < 7; ++i) {
        const int trow = (ro + i) * 14 + co;
        #pragma unroll
        for (int jd = 0; jd < 7; ++jd) {
            const unsigned short* kp = Ks + (trow + jd) * KV_PAD;
            float s = 0.f;
            #pragma unroll
            for (int d8 = 0; d8 < 4; ++d8) {
                s16x8 kv = *(const s16x8*)(kp + d8 * 8);
                #pragma unroll
                for (int e = 0; e < 8; ++e)
                    s = fmaf(qf[d8 * 8 + e], b2f((unsigned short)kv[e]), s);
            }
            s *= 0.17677669529663687f;   // 1/sqrt(32)
            mx = fmaxf(mx, s);
            srow[i * 7 + jd] = s;
        }
    }

    // ---- exp + sum (private row; no cross-lane -> no barrier needed)
    float sum = 0.f;
    #pragma unroll 7
    for (int j = 0; j < 49; ++j) {
        const float e = __expf(srow[j] - mx);
        srow[j] = e;
        sum += e;
    }
    const float inv = 1.0f / sum;

    // ---- PV accumulate (normalize folded into the final scale)
    float acc[32] = {};
    for (int i = 0; i < 7; ++i) {
        const int trow = (ro + i) * 14 + co;
        #pragma unroll
        for (int jd = 0; jd < 7; ++jd) {
            const float p = srow[i * 7 + jd];
            const unsigned short* vp = Vs + (trow + jd) * KV_PAD;
            #pragma unroll
            for (int d8 = 0; d8 < 4; ++d8) {
                s16x8 vv = *(const s16x8*)(vp + d8 * 8);
                #pragma unroll
                for (int e = 0; e < 8; ++e)
                    acc[d8 * 8 + e] = fmaf(p, b2f((unsigned short)vv[e]), acc[d8 * 8 + e]);
            }
        }
    }

    // ---- store out (bf16)
    unsigned short* op = att + (size_t)tok * DMODEL + head * 32;
    #pragma unroll
    for (int d4 = 0; d4 < 8; ++d4) {
        ushort4 o;
        o.x = f2b(acc[d4 * 4 + 0] * inv);
        o.y = f2b(acc[d4 * 4 + 1] * inv);
        o.z = f2b(acc[d4 * 4 + 2] * inv);
        o.w = f2b(acc[d4 * 4 + 3] * inv);
        *(ushort4*)(op + d4 * 4) = o;
    }
}

// ---------------------------------------------------------------------------
// out = LayerNorm(resid + y) * g + beta; fp32 out + optional bf16 out.
// ---------------------------------------------------------------------------
__global__ __launch_bounds__(256)
void add_ln_kernel(const float* __restrict__ resid, const float* __restrict__ y,
                   const float* __restrict__ g, const float* __restrict__ beta,
                   float* __restrict__ outf, unsigned short* __restrict__ outb)
{
    const int row = blockIdx.x;
    const int tid = threadIdx.x;
    const size_t base = (size_t)row * DMODEL;

    __shared__ float red[4];
    __shared__ float stats[2];

    const float t = resid[base + tid] + y[base + tid];

    float s = t;
    #pragma unroll
    for (int o = 32; o > 0; o >>= 1) s += __shfl_down(s, o, 64);
    const int wave = tid >> 6, lane = tid & 63;
    if (lane == 0) red[wave] = s;
    __syncthreads();
    if (tid == 0) stats[0] = (red[0] + red[1] + red[2] + red[3]) * (1.0f / 256.0f);
    __syncthreads();
    const float m = stats[0];

    const float dv = t - m;
    float s2 = dv * dv;
    #pragma unroll
    for (int o = 32; o > 0; o >>= 1) s2 += __shfl_down(s2, o, 64);
    if (lane == 0) red[wave] = s2;
    __syncthreads();
    if (tid == 0)
        stats[1] = rsqrtf((red[0] + red[1] + red[2] + red[3]) * (1.0f / 256.0f) + 1e-5f);
    __syncthreads();
    const float r = stats[1];

    const float o = dv * r * g[tid] + beta[tid];
    outf[base + tid] = o;
    if (outb) outb[base + tid] = f2b(o);
}

// ---------------------------------------------------------------------------
extern "C" void kernel_launch(void* const* d_in, const int* in_sizes, int n_in,
                              void* d_out, int out_size, void* d_ws, size_t ws_size,
                              hipStream_t stream)
{
    const float* x      = (const float*)d_in[0];
    const float* W_qkv  = (const float*)d_in[1];
    const float* b_qkv  = (const float*)d_in[2];
    const float* W_proj = (const float*)d_in[3];
    const float* b_proj = (const float*)d_in[4];
    const float* W1     = (const float*)d_in[5];
    const float* b1     = (const float*)d_in[6];
    const float* W2     = (const float*)d_in[7];
    const float* b2     = (const float*)d_in[8];
    const float* g1     = (const float*)d_in[9];
    const float* be1    = (const float*)d_in[10];
    const float* g2     = (const float*)d_in[11];
    const float* be2    = (const float*)d_in[12];
    float* out = (float*)d_out;

    char* ws = (char*)d_ws;
    const int M = NTOK;  // 12544

    // Workspace layout:
    // R1: qkvb bf16 [M][768] then h bf16 [M][1024]
    // R2: xb bf16 then attb bf16 [M][256]
    // R3: y f32 then f f32 [M][256]
    // R4: xn f32 [M][256]
    // R5: xnb bf16 [M][256]
    // R6: bf16 transposed weights
    unsigned short* qkvb = (unsigned short*)ws;
    unsigned short* h    = (unsigned short*)ws;
    unsigned short* xb   = (unsigned short*)(ws + 38535168);
    unsigned short* attb = xb;
    float*          y    = (float*)(ws + 44957696);
    float*          f    = y;
    float*          xn   = (float*)(ws + 57802752);
    unsigned short* xnb  = (unsigned short*)(ws + 70647808);
    unsigned short* Wqb  = (unsigned short*)(ws + 77070336);
    unsigned short* Wpb  = Wqb + 196608;
    unsigned short* W1b  = Wpb + 65536;
    unsigned short* W2b  = W1b + 262144;

    dim3 blk(256);

    // 0) cast x + cast/transpose weights to bf16
    prep_kernel<<<dim3(6208), blk, 0, stream>>>(x, W_qkv, W_proj, W1, W2, xb, Wqb, Wpb, W1b, W2b);

    // 1) qkvb = bf16(x @ W_qkv + b_qkv)
    gemm_mfma<<<dim3(6, 98), blk, 0, stream>>>(xb, Wqb, b_qkv, nullptr, qkvb, M, 768, 256, 0);

    // 2) tiled neighborhood attention -> attb (bf16)
    natt_kernel<<<dim3(1568), dim3(64), 0, stream>>>(qkvb, attb);

    // 3) y = att @ W_proj + b_proj (f32)
    gemm_mfma<<<dim3(2, 98), blk, 0, stream>>>(attb, Wpb, b_proj, y, nullptr, M, 256, 256, 0);

    // 4) xn = LN(x + y)  (f32 + bf16)
    add_ln_kernel<<<dim3(M), blk, 0, stream>>>(x, y, g1, be1, xn, xnb);

    // 5) h = relu(xn @ W1 + b1)  (bf16 only)
    gemm_mfma<<<dim3(8, 98), blk, 0, stream>>>(xnb, W1b, b1, nullptr, h, M, 1024, 256, 1);

    // 6) f = h @ W2 + b2  (f32)
    gemm_mfma<<<dim3(2, 98), blk, 0, stream>>>(h, W2b, b2, f, M == 0 ? (unsigned short*)nullptr : nullptr, M, 256, 1024, 0);

    // 7) out = LN(xn + f)
    add_ln_kernel<<<dim3(M), blk, 0, stream>>>(xn, f, g2, be2, out, nullptr);
}